// Round 23
// baseline (464.796 us; speedup 1.0000x reference)
//
#include <hip/hip_runtime.h>
#include <hip/hip_bf16.h>
#include <cmath>

// CapsNet forward. R21/R22 conv2 (2-image M-packed, 3-product split-bf16 MFMA,
// kx-parity LDS, K-split x2 parts, setprio) + prep_all verbatim.
// routing_fused: 1024 thr (64 ng x 16 k, u[18] x 2 img), LDS-staged x,
// wave-shfl fp64 reductions (16x16 wave partials) -> 16 waves/CU (was 8).
// ws: wstg 21.2 | c1g 96.5 | xcaps0 9.4 | xcaps1 9.4 = 136.5 MB (proven).

typedef float f32x4 __attribute__((ext_vector_type(4)));
typedef short s16x8 __attribute__((ext_vector_type(8)));
typedef unsigned int u32;

static __device__ __forceinline__ short f2bf(float x) {
  __hip_bfloat16 h = __float2bfloat16(x);
  return *reinterpret_cast<short*>(&h);
}
static __device__ __forceinline__ float bf2f(short s) {
  __hip_bfloat16 h;
  *reinterpret_cast<short*>(&h) = s;
  return __bfloat162float(h);
}
static __device__ __forceinline__ void stage16(const short* g, short* l) {
  __builtin_amdgcn_global_load_lds(
      (const __attribute__((address_space(1))) u32*)(const void*)g,
      (__attribute__((address_space(3))) u32*)(void*)l, 16, 0, 0);
}

// c1g chunk layout: even section 192 rows x 64 shorts | odd section 176 x 64.
#define CHUNK_SHORTS 23552  // (192+176)*64
#define ODD_OFS 12288       // 192*64
#define EV_IMG 12288        // even-section shorts per image in LDS
#define OD_IMG 11264        // odd-section shorts per image in LDS

// ---------------- merged prep: w2->wstg (coalesced) | conv1->c1g ----------------
__global__ __launch_bounds__(256) void prep_all(
    const float* __restrict__ w2, s16x8* __restrict__ wstg,
    const float* __restrict__ data, const float* __restrict__ w1,
    const float* __restrict__ b1, short* __restrict__ c1g) {
  __shared__ float sbuf[12784];  // w2: 10368 | conv1: simg 1008 + c1buf 11776
  const int t = threadIdx.x;
  if (blockIdx.x < 512) {
    const int b = blockIdx.x;
    const int chunk = b >> 6;
    const int kg = (b >> 4) & 3;
    const int cot = b & 15;
    const int co0 = cot * 16;
    const size_t gbase = (size_t)(chunk * 32 + kg * 8) * 81;
    for (int i = t; i < 10368; i += 256) {
      const int r = i / 648, e = i - r * 648;
      sbuf[i] = w2[(size_t)(co0 + r) * 20736 + gbase + e];
    }
    __syncthreads();
    for (int p = t; p < 1296; p += 256) {
      const int tap = p >> 4, co = p & 15;
      s16x8 hi, lo;
#pragma unroll
      for (int i = 0; i < 8; ++i) {
        const float x = sbuf[co * 648 + i * 81 + tap];
        const short h = f2bf(x);
        hi[i] = h;
        lo[i] = f2bf(x - bf2f(h));
      }
      const size_t T = (size_t)(chunk * 81 + tap);
      wstg[T * 2048 + kg * 256 + co0 + co] = hi;
      wstg[T * 2048 + 1024 + kg * 256 + co0 + co] = lo;
    }
    return;
  }
  // ---- conv1 -> c1g: block = (img, chunk-half); LDS-assemble + coalesced flush
  const int cb = blockIdx.x - 512;
  const int img = cb >> 1;
  const int chh = cb & 1;            // chunks chh*4 .. chh*4+3
  float* simg = sbuf;                // 28 rows x 36 (1008 floats)
  short* c1buf = (short*)&sbuf[1008];// 23,552 shorts
  for (int i = t; i < 784; i += 256)
    simg[(i / 28) * 36 + (i % 28)] = data[img * 784 + i];
  __syncthreads();
  for (int cc = 0; cc < 4; ++cc) {
    const int chunk = chh * 4 + cc;
    for (int task = t; task < 608; task += 256) {
      const int ci = task & 31;
      const int y = task >> 5;       // 0..18
      const int ch = chunk * 32 + ci;
      const float* wr = w1 + ch * 81;
      float acc[20];
      const float bz = b1[ch];
#pragma unroll
      for (int x = 0; x < 20; ++x) acc[x] = bz;
#pragma unroll
      for (int ky = 0; ky < 9; ++ky) {
        float rr[28];
#pragma unroll
        for (int q = 0; q < 7; ++q)
          *(float4*)&rr[q * 4] = *(const float4*)&simg[(y + ky) * 36 + q * 4];
#pragma unroll
        for (int kx = 0; kx < 9; ++kx) {
          const float w = wr[ky * 9 + kx];
#pragma unroll
          for (int x = 0; x < 20; ++x) acc[x] = fmaf(w, rr[x + kx], acc[x]);
        }
      }
      const int kg = ci >> 3, il = ci & 7;
#pragma unroll
      for (int x = 0; x < 19; ++x) {  // x==19 dead
        const int xh = x >> 1;
        const int r = (x & 1) ? (y * 9 + xh) : (y * 10 + xh);
        short* base = c1buf + ((x & 1) ? ODD_OFS : 0);
        const float v = fmaxf(acc[x], 0.f);
        const short hi = f2bf(v);
        const short lo = f2bf(v - bf2f(hi));
        base[r * 64 + (((kg + r) & 7) << 3) + il] = hi;
        base[r * 64 + (((kg + 4 + r) & 7) << 3) + il] = lo;
      }
    }
    __syncthreads();
    {
      s16x8* dst = (s16x8*)(c1g + (size_t)(img * 8 + chunk) * CHUNK_SHORTS);
      const s16x8* srcb = (const s16x8*)c1buf;
      for (int i = t; i < 2944; i += 256) dst[i] = srcb[i];
    }
    __syncthreads();
  }
}

// -------- conv2 via MFMA, 2-image M-packed (5 tiles), N=32/wave, K-split --------
__global__ __launch_bounds__(256) void conv2_mfma(
    const short* __restrict__ c1g, const short* __restrict__ wstg,
    const float* __restrict__ b2, float* __restrict__ xcaps0,
    float* __restrict__ xcaps1) {
  const int t = threadIdx.x;
  const int bid = blockIdx.x;        // 512
  const int xcd = bid & 7;
  const int ksp = xcd & 1;           // K half (chunks ksp*4 .. +4)
  const int coh = (xcd >> 1) & 1;    // co half
  const int pair = (bid >> 3) * 2 + (xcd >> 2);
  const int img0 = pair * 2;
  const int lane = t & 63;
  const int wv = t >> 6;             // 0..3
  const int r16 = lane & 15;
  const int kg = lane >> 4;

  __shared__ short c1[24576];        // 49,152 B: 2 images' parity sections

  int arowE[5], arowO[5], imE[5], imO[5];
#pragma unroll
  for (int m = 0; m < 5; ++m) {
    const int s = m * 16 + r16;
    const int im = (s >= 36) ? 1 : 0;
    int p = s - 36 * im;
    if (p > 35) p = 35;              // slots 72..79: clamp-broadcast, discarded
    const int oy = p / 6, ox = p % 6;
    arowE[m] = oy * 20 + ox;
    arowO[m] = oy * 18 + ox;
    imE[m] = im * EV_IMG;
    imO[m] = im * OD_IMG;
  }
  int bOff[2], con[2];
  float bias[2];
#pragma unroll
  for (int j = 0; j < 2; ++j) {
    const int co = coh * 128 + wv * 32 + j * 16 + r16;
    con[j] = co;
    bOff[j] = kg * 256 + co;
    bias[j] = (ksp == 0) ? b2[co] : 0.f;
  }
  float* xcp = (ksp == 0) ? xcaps0 : xcaps1;

  const f32x4 vzero = {0.f, 0.f, 0.f, 0.f};
  f32x4 acc[5][2];
#pragma unroll
  for (int m = 0; m < 5; ++m)
#pragma unroll
    for (int j = 0; j < 2; ++j) acc[m][j] = vzero;

  const s16x8* wsv = (const s16x8*)wstg;

  for (int cc = 0; cc < 4; ++cc) {
    const int chunk = ksp * 4 + cc;
    const short* src0 = c1g + (size_t)(img0 * 8 + chunk) * CHUNK_SHORTS;
    const short* src1 = c1g + (size_t)((img0 + 1) * 8 + chunk) * CHUNK_SHORTS;
    const size_t bb = (size_t)chunk * 81 * 2048;

    // ==== EVEN pass ====
    __syncthreads();
    for (int c = wv; c < 48; c += 4) {
      const short* s = (c < 24) ? (src0 + c * 512) : (src1 + (c - 24) * 512);
      stage16(s + lane * 8, &c1[c * 512]);
    }
    __syncthreads();
    {
      s16x8 BHc[2], BLc[2];
#pragma unroll
      for (int j = 0; j < 2; ++j) {
        BHc[j] = wsv[bb + bOff[j]];
        BLc[j] = wsv[bb + bOff[j] + 1024];
      }
      for (int ky = 0; ky < 9; ++ky) {
#pragma unroll
        for (int kxi = 0; kxi < 5; ++kxi) {
          s16x8 BHn[2], BLn[2];
          if (!(ky == 8 && kxi == 4)) {
            const int nky = (kxi == 4) ? ky + 1 : ky;
            const int nkxi = (kxi == 4) ? 0 : kxi + 1;
            const size_t nb = bb + (size_t)(nky * 9 + 2 * nkxi) * 2048;
#pragma unroll
            for (int j = 0; j < 2; ++j) {
              BHn[j] = wsv[nb + bOff[j]];
              BLn[j] = wsv[nb + bOff[j] + 1024];
            }
          }
          s16x8 AH[5], AL[5];
#pragma unroll
          for (int m = 0; m < 5; ++m) {
            const int r = arowE[m] + ky * 10 + kxi;
            AH[m] = *(const s16x8*)&c1[imE[m] + r * 64 + (((kg + r) & 7) << 3)];
            AL[m] = *(const s16x8*)&c1[imE[m] + r * 64 + (((kg + 4 + r) & 7) << 3)];
          }
          __builtin_amdgcn_s_setprio(1);
#pragma unroll
          for (int m = 0; m < 5; ++m)
#pragma unroll
            for (int j = 0; j < 2; ++j)
              acc[m][j] = __builtin_amdgcn_mfma_f32_16x16x32_bf16(AH[m], BHc[j], acc[m][j], 0, 0, 0);
#pragma unroll
          for (int m = 0; m < 5; ++m)
#pragma unroll
            for (int j = 0; j < 2; ++j)
              acc[m][j] = __builtin_amdgcn_mfma_f32_16x16x32_bf16(AL[m], BHc[j], acc[m][j], 0, 0, 0);
#pragma unroll
          for (int m = 0; m < 5; ++m)
#pragma unroll
            for (int j = 0; j < 2; ++j)
              acc[m][j] = __builtin_amdgcn_mfma_f32_16x16x32_bf16(AH[m], BLc[j], acc[m][j], 0, 0, 0);
          __builtin_amdgcn_s_setprio(0);
#pragma unroll
          for (int j = 0; j < 2; ++j) { BHc[j] = BHn[j]; BLc[j] = BLn[j]; }
        }
      }
    }

    // ==== ODD pass ====
    __syncthreads();
    for (int c = wv; c < 44; c += 4) {
      const short* s = (c < 22) ? (src0 + ODD_OFS + c * 512)
                                : (src1 + ODD_OFS + (c - 22) * 512);
      stage16(s + lane * 8, &c1[c * 512]);
    }
    __syncthreads();
    {
      s16x8 BHc[2], BLc[2];
#pragma unroll
      for (int j = 0; j < 2; ++j) {
        BHc[j] = wsv[bb + 2048 + bOff[j]];
        BLc[j] = wsv[bb + 2048 + bOff[j] + 1024];
      }
      for (int ky = 0; ky < 9; ++ky) {
#pragma unroll
        for (int kxi = 0; kxi < 4; ++kxi) {
          s16x8 BHn[2], BLn[2];
          if (!(ky == 8 && kxi == 3)) {
            const int nky = (kxi == 3) ? ky + 1 : ky;
            const int nkxi = (kxi == 3) ? 0 : kxi + 1;
            const size_t nb = bb + (size_t)(nky * 9 + 2 * nkxi + 1) * 2048;
#pragma unroll
            for (int j = 0; j < 2; ++j) {
              BHn[j] = wsv[nb + bOff[j]];
              BLn[j] = wsv[nb + bOff[j] + 1024];
            }
          }
          s16x8 AH[5], AL[5];
#pragma unroll
          for (int m = 0; m < 5; ++m) {
            const int r = arowO[m] + ky * 9 + kxi;
            AH[m] = *(const s16x8*)&c1[imO[m] + r * 64 + (((kg + r) & 7) << 3)];
            AL[m] = *(const s16x8*)&c1[imO[m] + r * 64 + (((kg + 4 + r) & 7) << 3)];
          }
          __builtin_amdgcn_s_setprio(1);
#pragma unroll
          for (int m = 0; m < 5; ++m)
#pragma unroll
            for (int j = 0; j < 2; ++j)
              acc[m][j] = __builtin_amdgcn_mfma_f32_16x16x32_bf16(AH[m], BHc[j], acc[m][j], 0, 0, 0);
#pragma unroll
          for (int m = 0; m < 5; ++m)
#pragma unroll
            for (int j = 0; j < 2; ++j)
              acc[m][j] = __builtin_amdgcn_mfma_f32_16x16x32_bf16(AL[m], BHc[j], acc[m][j], 0, 0, 0);
#pragma unroll
          for (int m = 0; m < 5; ++m)
#pragma unroll
            for (int j = 0; j < 2; ++j)
              acc[m][j] = __builtin_amdgcn_mfma_f32_16x16x32_bf16(AH[m], BLc[j], acc[m][j], 0, 0, 0);
          __builtin_amdgcn_s_setprio(0);
#pragma unroll
          for (int j = 0; j < 2; ++j) { BHc[j] = BHn[j]; BLc[j] = BLn[j]; }
        }
      }
    }
  }

  // store partial: slot s = m*16 + kg*4 + jj -> (img, pos); col = r16 (co)
#pragma unroll
  for (int m = 0; m < 5; ++m) {
#pragma unroll
    for (int jj = 0; jj < 4; ++jj) {
      const int s = m * 16 + kg * 4 + jj;
      if (s < 72) {
        const int im = (s >= 36) ? 1 : 0;
        const int p = s - 36 * im;
#pragma unroll
        for (int j = 0; j < 2; ++j) {
          const int co = con[j];
          const int n = (co & 31) * 36 + p;
          xcp[((size_t)(img0 + im) * 1152 + n) * 8 + (co >> 5)] =
              acc[m][j][jj] + bias[j];
        }
      }
    }
  }
}

// ------- routing: 1024 thr (64 ng x 16 k), LDS-staged x, shfl reductions -------
__global__ __launch_bounds__(1024) void routing_fused(const float* __restrict__ xcaps0,
                                                      const float* __restrict__ xcaps1,
                                                      const float* __restrict__ W,
                                                      float* __restrict__ out) {
  const int o = blockIdx.x >> 7;     // 0..9 (o-major: same-o blocks share W)
  const int bp = blockIdx.x & 127;   // image pair
  const int b0 = bp * 2, b1 = b0 + 1;
  const int t = threadIdx.x;
  const int k = t & 15, ng = t >> 4;       // ng 0..63
  const int lane = t & 63, wavei = t >> 6; // 0..15
  __shared__ float xs0[1152 * 8];
  __shared__ float xs1[1152 * 8];
  __shared__ double srA[16][16], srB[16][16], srC[16][16], srD[16][16];
  __shared__ float s0s[16], s1s[16];
  __shared__ float sv0s, sv1s;
  __shared__ double f0s, f1s;

  {
    const float4* p00 = (const float4*)(xcaps0 + (size_t)b0 * 9216);
    const float4* p01 = (const float4*)(xcaps1 + (size_t)b0 * 9216);
    const float4* p10 = (const float4*)(xcaps0 + (size_t)b1 * 9216);
    const float4* p11 = (const float4*)(xcaps1 + (size_t)b1 * 9216);
    float4* d0 = (float4*)xs0;
    float4* d1 = (float4*)xs1;
    for (int i = t; i < 2304; i += 1024) {
      float4 a = p00[i], b = p01[i];
      float4 c = p10[i], d = p11[i];
      float4 s0, s1;
      s0.x = a.x + b.x; s0.y = a.y + b.y; s0.z = a.z + b.z; s0.w = a.w + b.w;
      s1.x = c.x + d.x; s1.y = c.y + d.y; s1.z = c.z + d.z; s1.w = c.w + d.w;
      d0[i] = s0;
      d1[i] = s1;
    }
  }
  __syncthreads();

  const int n0 = ng * 18;
  float u0[18], u1[18];
  const float* wp = W + ((size_t)(n0 * 10 + o) * 16 + k) * 8;
#pragma unroll
  for (int i = 0; i < 18; ++i) {
    const float* wq = wp + (size_t)i * 1280;
    const float4 wa = *(const float4*)wq;
    const float4 wb = *(const float4*)(wq + 4);
    const float4 xa0 = *(const float4*)&xs0[(n0 + i) * 8];
    const float4 xb0 = *(const float4*)&xs0[(n0 + i) * 8 + 4];
    const float4 xa1 = *(const float4*)&xs1[(n0 + i) * 8];
    const float4 xb1 = *(const float4*)&xs1[(n0 + i) * 8 + 4];
    u0[i] = wa.x * xa0.x + wa.y * xa0.y + wa.z * xa0.z + wa.w * xa0.w
          + wb.x * xb0.x + wb.y * xb0.y + wb.z * xb0.z + wb.w * xb0.w;
    u1[i] = wa.x * xa1.x + wa.y * xa1.y + wa.z * xa1.z + wa.w * xa1.w
          + wb.x * xb1.x + wb.y * xb1.y + wb.z * xb1.z + wb.w * xb1.w;
  }

  // ---- pass 1: uniform c = 1/1152 ----
  {
    double S0 = 0.0, S1 = 0.0;
#pragma unroll
    for (int i = 0; i < 18; ++i) { S0 += (double)u0[i]; S1 += (double)u1[i]; }
    S0 += __shfl_xor(S0, 16); S0 += __shfl_xor(S0, 32);
    S1 += __shfl_xor(S1, 16); S1 += __shfl_xor(S1, 32);
    if (lane < 16) { srA[wavei][lane] = S0; srB[wavei][lane] = S1; }
  }
  __syncthreads();
  if (t < 32) {
    const int g = t >> 4, kk = t & 15;
    double tot = 0.0;
#pragma unroll
    for (int w = 0; w < 16; ++w) tot += (g == 0) ? srA[w][kk] : srB[w][kk];
    if (g == 0) s0s[kk] = (float)(tot * (double)(1.0f / 1152.0f));
    else        s1s[kk] = (float)(tot * (double)(1.0f / 1152.0f));
  }
  __syncthreads();
  if (t < 2) {
    const float* ss = (t == 0) ? s0s : s1s;
    double sn = 0.0;
#pragma unroll
    for (int kk = 0; kk < 16; ++kk) sn += (double)ss[kk] * (double)ss[kk];
    const double f = sn / ((1.0 + sn) * sqrt(sn));
    double sv = 0.0;
#pragma unroll
    for (int kk = 0; kk < 16; ++kk) sv += (double)ss[kk] * f;
    if (t == 0) sv0s = (float)sv; else sv1s = (float)sv;
  }
  __syncthreads();
  const float v10 = sv0s, v11 = sv1s;

  // ---- pass 2: logits u*sv1 ----
  {
    double E0 = 0.0, EU0 = 0.0, E1 = 0.0, EU1 = 0.0;
#pragma unroll
    for (int i = 0; i < 18; ++i) {
      const float e0 = expf(u0[i] * v10);
      E0 += (double)e0;
      EU0 += (double)e0 * (double)u0[i];
      const float e1 = expf(u1[i] * v11);
      E1 += (double)e1;
      EU1 += (double)e1 * (double)u1[i];
    }
    E0 += __shfl_xor(E0, 16); E0 += __shfl_xor(E0, 32);
    EU0 += __shfl_xor(EU0, 16); EU0 += __shfl_xor(EU0, 32);
    E1 += __shfl_xor(E1, 16); E1 += __shfl_xor(E1, 32);
    EU1 += __shfl_xor(EU1, 16); EU1 += __shfl_xor(EU1, 32);
    if (lane < 16) {
      srA[wavei][lane] = E0; srB[wavei][lane] = EU0;
      srC[wavei][lane] = E1; srD[wavei][lane] = EU1;
    }
  }
  __syncthreads();
  if (t < 32) {
    const int g = t >> 4, kk = t & 15;
    double te = 0.0, tu = 0.0;
#pragma unroll
    for (int w = 0; w < 16; ++w) {
      te += (g == 0) ? srA[w][kk] : srC[w][kk];
      tu += (g == 0) ? srB[w][kk] : srD[w][kk];
    }
    if (g == 0) s0s[kk] = (float)(tu / te);
    else        s1s[kk] = (float)(tu / te);
  }
  __syncthreads();
  if (t < 2) {
    const float* ss = (t == 0) ? s0s : s1s;
    double sn = 0.0;
#pragma unroll
    for (int kk = 0; kk < 16; ++kk) sn += (double)ss[kk] * (double)ss[kk];
    const double f = sn / ((1.0 + sn) * sqrt(sn));
    double sv = 0.0;
#pragma unroll
    for (int kk = 0; kk < 16; ++kk) sv += (double)ss[kk] * f;
    if (t == 0) sv0s = v10 + (float)sv; else sv1s = v11 + (float)sv;
  }
  __syncthreads();
  const float v20 = sv0s, v21 = sv1s;

  // ---- pass 3 -> output ----
  {
    double E0 = 0.0, EU0 = 0.0, E1 = 0.0, EU1 = 0.0;
#pragma unroll
    for (int i = 0; i < 18; ++i) {
      const float e0 = expf(u0[i] * v20);
      E0 += (double)e0;
      EU0 += (double)e0 * (double)u0[i];
      const float e1 = expf(u1[i] * v21);
      E1 += (double)e1;
      EU1 += (double)e1 * (double)u1[i];
    }
    E0 += __shfl_xor(E0, 16); E0 += __shfl_xor(E0, 32);
    EU0 += __shfl_xor(EU0, 16); EU0 += __shfl_xor(EU0, 32);
    E1 += __shfl_xor(E1, 16); E1 += __shfl_xor(E1, 32);
    EU1 += __shfl_xor(EU1, 16); EU1 += __shfl_xor(EU1, 32);
    if (lane < 16) {
      srA[wavei][lane] = E0; srB[wavei][lane] = EU0;
      srC[wavei][lane] = E1; srD[wavei][lane] = EU1;
    }
  }
  __syncthreads();
  if (t < 32) {
    const int g = t >> 4, kk = t & 15;
    double te = 0.0, tu = 0.0;
#pragma unroll
    for (int w = 0; w < 16; ++w) {
      te += (g == 0) ? srA[w][kk] : srC[w][kk];
      tu += (g == 0) ? srB[w][kk] : srD[w][kk];
    }
    if (g == 0) s0s[kk] = (float)(tu / te);
    else        s1s[kk] = (float)(tu / te);
  }
  __syncthreads();
  if (t < 2) {
    const float* ss = (t == 0) ? s0s : s1s;
    double sn = 0.0;
#pragma unroll
    for (int kk = 0; kk < 16; ++kk) sn += (double)ss[kk] * (double)ss[kk];
    if (t == 0) f0s = sn / ((1.0 + sn) * sqrt(sn));
    else        f1s = sn / ((1.0 + sn) * sqrt(sn));
  }
  __syncthreads();
  if (t < 32) {
    const int g = t >> 4, kk = t & 15;
    const int b = (g == 0) ? b0 : b1;
    const double f = (g == 0) ? f0s : f1s;
    const float s = (g == 0) ? s0s[kk] : s1s[kk];
    out[b * 160 + o * 16 + kk] = (float)((double)s * f);
  }
}

extern "C" void kernel_launch(void* const* d_in, const int* in_sizes, int n_in,
                              void* d_out, int out_size, void* d_ws, size_t ws_size,
                              hipStream_t stream) {
  const float* data = (const float*)d_in[0];
  const float* w1   = (const float*)d_in[1];
  const float* b1   = (const float*)d_in[2];
  const float* w2   = (const float*)d_in[3];
  const float* b2   = (const float*)d_in[4];
  const float* W    = (const float*)d_in[5];
  float* out = (float*)d_out;

  short* wstg   = (short*)d_ws;               // 10,616,832 shorts (21.2 MB)
  short* c1g    = wstg + 10616832;            // 48,234,496 shorts (96.5 MB)
  float* xcaps0 = (float*)(c1g + 48234496);   //  2,359,296 floats (9.4 MB)
  float* xcaps1 = xcaps0 + 2359296;           //  2,359,296 floats (9.4 MB)

  prep_all<<<1024, 256, 0, stream>>>(w2, (s16x8*)wstg, data, w1, b1, c1g);
  conv2_mfma<<<512, 256, 0, stream>>>(c1g, wstg, b2, xcaps0, xcaps1);
  routing_fused<<<1280, 1024, 0, stream>>>(xcaps0, xcaps1, W, out);
}

// Round 24
// 438.805 us; speedup vs baseline: 1.0592x; 1.0592x over previous
//
#include <hip/hip_runtime.h>
#include <hip/hip_bf16.h>
#include <cmath>

// CapsNet forward — FINAL (R22 restore, 440 us best-known).
// conv2: 2-image M-packed (5 M-tiles/72 pos), 3-product split-bf16 MFMA,
//   kx-parity LDS (49,152 B), N=32/wave, K-split x2 separate parts, setprio.
// prep_all: coalesced w2 -> wstg; LDS-assembled conv1 -> c1g.
// routing_fused: 512 thr (32 ng x 16 k, u[36] x 2 img), LDS-staged x,
//   wave-shfl fp64 reductions (8x16 wave partials).
// ws: wstg 21.2 | c1g 96.5 | xcaps0 9.4 | xcaps1 9.4 = 136.5 MB (proven).

typedef float f32x4 __attribute__((ext_vector_type(4)));
typedef short s16x8 __attribute__((ext_vector_type(8)));
typedef unsigned int u32;

static __device__ __forceinline__ short f2bf(float x) {
  __hip_bfloat16 h = __float2bfloat16(x);
  return *reinterpret_cast<short*>(&h);
}
static __device__ __forceinline__ float bf2f(short s) {
  __hip_bfloat16 h;
  *reinterpret_cast<short*>(&h) = s;
  return __bfloat162float(h);
}
static __device__ __forceinline__ void stage16(const short* g, short* l) {
  __builtin_amdgcn_global_load_lds(
      (const __attribute__((address_space(1))) u32*)(const void*)g,
      (__attribute__((address_space(3))) u32*)(void*)l, 16, 0, 0);
}

// c1g chunk layout: even section 192 rows x 64 shorts | odd section 176 x 64.
#define CHUNK_SHORTS 23552  // (192+176)*64
#define ODD_OFS 12288       // 192*64
#define EV_IMG 12288        // even-section shorts per image in LDS
#define OD_IMG 11264        // odd-section shorts per image in LDS

// ---------------- merged prep: w2->wstg (coalesced) | conv1->c1g ----------------
__global__ __launch_bounds__(256) void prep_all(
    const float* __restrict__ w2, s16x8* __restrict__ wstg,
    const float* __restrict__ data, const float* __restrict__ w1,
    const float* __restrict__ b1, short* __restrict__ c1g) {
  __shared__ float sbuf[12784];  // w2: 10368 | conv1: simg 1008 + c1buf 11776
  const int t = threadIdx.x;
  if (blockIdx.x < 512) {
    const int b = blockIdx.x;
    const int chunk = b >> 6;
    const int kg = (b >> 4) & 3;
    const int cot = b & 15;
    const int co0 = cot * 16;
    const size_t gbase = (size_t)(chunk * 32 + kg * 8) * 81;
    for (int i = t; i < 10368; i += 256) {
      const int r = i / 648, e = i - r * 648;
      sbuf[i] = w2[(size_t)(co0 + r) * 20736 + gbase + e];
    }
    __syncthreads();
    for (int p = t; p < 1296; p += 256) {
      const int tap = p >> 4, co = p & 15;
      s16x8 hi, lo;
#pragma unroll
      for (int i = 0; i < 8; ++i) {
        const float x = sbuf[co * 648 + i * 81 + tap];
        const short h = f2bf(x);
        hi[i] = h;
        lo[i] = f2bf(x - bf2f(h));
      }
      const size_t T = (size_t)(chunk * 81 + tap);
      wstg[T * 2048 + kg * 256 + co0 + co] = hi;
      wstg[T * 2048 + 1024 + kg * 256 + co0 + co] = lo;
    }
    return;
  }
  // ---- conv1 -> c1g: block = (img, chunk-half); LDS-assemble + coalesced flush
  const int cb = blockIdx.x - 512;
  const int img = cb >> 1;
  const int chh = cb & 1;            // chunks chh*4 .. chh*4+3
  float* simg = sbuf;                // 28 rows x 36 (1008 floats)
  short* c1buf = (short*)&sbuf[1008];// 23,552 shorts
  for (int i = t; i < 784; i += 256)
    simg[(i / 28) * 36 + (i % 28)] = data[img * 784 + i];
  __syncthreads();
  for (int cc = 0; cc < 4; ++cc) {
    const int chunk = chh * 4 + cc;
    for (int task = t; task < 608; task += 256) {
      const int ci = task & 31;
      const int y = task >> 5;       // 0..18
      const int ch = chunk * 32 + ci;
      const float* wr = w1 + ch * 81;
      float acc[20];
      const float bz = b1[ch];
#pragma unroll
      for (int x = 0; x < 20; ++x) acc[x] = bz;
#pragma unroll
      for (int ky = 0; ky < 9; ++ky) {
        float rr[28];
#pragma unroll
        for (int q = 0; q < 7; ++q)
          *(float4*)&rr[q * 4] = *(const float4*)&simg[(y + ky) * 36 + q * 4];
#pragma unroll
        for (int kx = 0; kx < 9; ++kx) {
          const float w = wr[ky * 9 + kx];
#pragma unroll
          for (int x = 0; x < 20; ++x) acc[x] = fmaf(w, rr[x + kx], acc[x]);
        }
      }
      const int kg = ci >> 3, il = ci & 7;
#pragma unroll
      for (int x = 0; x < 19; ++x) {  // x==19 dead
        const int xh = x >> 1;
        const int r = (x & 1) ? (y * 9 + xh) : (y * 10 + xh);
        short* base = c1buf + ((x & 1) ? ODD_OFS : 0);
        const float v = fmaxf(acc[x], 0.f);
        const short hi = f2bf(v);
        const short lo = f2bf(v - bf2f(hi));
        base[r * 64 + (((kg + r) & 7) << 3) + il] = hi;
        base[r * 64 + (((kg + 4 + r) & 7) << 3) + il] = lo;
      }
    }
    __syncthreads();
    {
      s16x8* dst = (s16x8*)(c1g + (size_t)(img * 8 + chunk) * CHUNK_SHORTS);
      const s16x8* srcb = (const s16x8*)c1buf;
      for (int i = t; i < 2944; i += 256) dst[i] = srcb[i];
    }
    __syncthreads();
  }
}

// -------- conv2 via MFMA, 2-image M-packed (5 tiles), N=32/wave, K-split --------
__global__ __launch_bounds__(256) void conv2_mfma(
    const short* __restrict__ c1g, const short* __restrict__ wstg,
    const float* __restrict__ b2, float* __restrict__ xcaps0,
    float* __restrict__ xcaps1) {
  const int t = threadIdx.x;
  const int bid = blockIdx.x;        // 512
  const int xcd = bid & 7;
  const int ksp = xcd & 1;           // K half (chunks ksp*4 .. +4)
  const int coh = (xcd >> 1) & 1;    // co half
  const int pair = (bid >> 3) * 2 + (xcd >> 2);
  const int img0 = pair * 2;
  const int lane = t & 63;
  const int wv = t >> 6;             // 0..3
  const int r16 = lane & 15;
  const int kg = lane >> 4;

  __shared__ short c1[24576];        // 49,152 B: 2 images' parity sections

  int arowE[5], arowO[5], imE[5], imO[5];
#pragma unroll
  for (int m = 0; m < 5; ++m) {
    const int s = m * 16 + r16;
    const int im = (s >= 36) ? 1 : 0;
    int p = s - 36 * im;
    if (p > 35) p = 35;              // slots 72..79: clamp-broadcast, discarded
    const int oy = p / 6, ox = p % 6;
    arowE[m] = oy * 20 + ox;
    arowO[m] = oy * 18 + ox;
    imE[m] = im * EV_IMG;
    imO[m] = im * OD_IMG;
  }
  int bOff[2], con[2];
  float bias[2];
#pragma unroll
  for (int j = 0; j < 2; ++j) {
    const int co = coh * 128 + wv * 32 + j * 16 + r16;
    con[j] = co;
    bOff[j] = kg * 256 + co;
    bias[j] = (ksp == 0) ? b2[co] : 0.f;
  }
  float* xcp = (ksp == 0) ? xcaps0 : xcaps1;

  const f32x4 vzero = {0.f, 0.f, 0.f, 0.f};
  f32x4 acc[5][2];
#pragma unroll
  for (int m = 0; m < 5; ++m)
#pragma unroll
    for (int j = 0; j < 2; ++j) acc[m][j] = vzero;

  const s16x8* wsv = (const s16x8*)wstg;

  for (int cc = 0; cc < 4; ++cc) {
    const int chunk = ksp * 4 + cc;
    const short* src0 = c1g + (size_t)(img0 * 8 + chunk) * CHUNK_SHORTS;
    const short* src1 = c1g + (size_t)((img0 + 1) * 8 + chunk) * CHUNK_SHORTS;
    const size_t bb = (size_t)chunk * 81 * 2048;

    // ==== EVEN pass ====
    __syncthreads();
    for (int c = wv; c < 48; c += 4) {
      const short* s = (c < 24) ? (src0 + c * 512) : (src1 + (c - 24) * 512);
      stage16(s + lane * 8, &c1[c * 512]);
    }
    __syncthreads();
    {
      s16x8 BHc[2], BLc[2];
#pragma unroll
      for (int j = 0; j < 2; ++j) {
        BHc[j] = wsv[bb + bOff[j]];
        BLc[j] = wsv[bb + bOff[j] + 1024];
      }
      for (int ky = 0; ky < 9; ++ky) {
#pragma unroll
        for (int kxi = 0; kxi < 5; ++kxi) {
          s16x8 BHn[2], BLn[2];
          if (!(ky == 8 && kxi == 4)) {
            const int nky = (kxi == 4) ? ky + 1 : ky;
            const int nkxi = (kxi == 4) ? 0 : kxi + 1;
            const size_t nb = bb + (size_t)(nky * 9 + 2 * nkxi) * 2048;
#pragma unroll
            for (int j = 0; j < 2; ++j) {
              BHn[j] = wsv[nb + bOff[j]];
              BLn[j] = wsv[nb + bOff[j] + 1024];
            }
          }
          s16x8 AH[5], AL[5];
#pragma unroll
          for (int m = 0; m < 5; ++m) {
            const int r = arowE[m] + ky * 10 + kxi;
            AH[m] = *(const s16x8*)&c1[imE[m] + r * 64 + (((kg + r) & 7) << 3)];
            AL[m] = *(const s16x8*)&c1[imE[m] + r * 64 + (((kg + 4 + r) & 7) << 3)];
          }
          __builtin_amdgcn_s_setprio(1);
#pragma unroll
          for (int m = 0; m < 5; ++m)
#pragma unroll
            for (int j = 0; j < 2; ++j)
              acc[m][j] = __builtin_amdgcn_mfma_f32_16x16x32_bf16(AH[m], BHc[j], acc[m][j], 0, 0, 0);
#pragma unroll
          for (int m = 0; m < 5; ++m)
#pragma unroll
            for (int j = 0; j < 2; ++j)
              acc[m][j] = __builtin_amdgcn_mfma_f32_16x16x32_bf16(AL[m], BHc[j], acc[m][j], 0, 0, 0);
#pragma unroll
          for (int m = 0; m < 5; ++m)
#pragma unroll
            for (int j = 0; j < 2; ++j)
              acc[m][j] = __builtin_amdgcn_mfma_f32_16x16x32_bf16(AH[m], BLc[j], acc[m][j], 0, 0, 0);
          __builtin_amdgcn_s_setprio(0);
#pragma unroll
          for (int j = 0; j < 2; ++j) { BHc[j] = BHn[j]; BLc[j] = BLn[j]; }
        }
      }
    }

    // ==== ODD pass ====
    __syncthreads();
    for (int c = wv; c < 44; c += 4) {
      const short* s = (c < 22) ? (src0 + ODD_OFS + c * 512)
                                : (src1 + ODD_OFS + (c - 22) * 512);
      stage16(s + lane * 8, &c1[c * 512]);
    }
    __syncthreads();
    {
      s16x8 BHc[2], BLc[2];
#pragma unroll
      for (int j = 0; j < 2; ++j) {
        BHc[j] = wsv[bb + 2048 + bOff[j]];
        BLc[j] = wsv[bb + 2048 + bOff[j] + 1024];
      }
      for (int ky = 0; ky < 9; ++ky) {
#pragma unroll
        for (int kxi = 0; kxi < 4; ++kxi) {
          s16x8 BHn[2], BLn[2];
          if (!(ky == 8 && kxi == 3)) {
            const int nky = (kxi == 3) ? ky + 1 : ky;
            const int nkxi = (kxi == 3) ? 0 : kxi + 1;
            const size_t nb = bb + (size_t)(nky * 9 + 2 * nkxi + 1) * 2048;
#pragma unroll
            for (int j = 0; j < 2; ++j) {
              BHn[j] = wsv[nb + bOff[j]];
              BLn[j] = wsv[nb + bOff[j] + 1024];
            }
          }
          s16x8 AH[5], AL[5];
#pragma unroll
          for (int m = 0; m < 5; ++m) {
            const int r = arowO[m] + ky * 9 + kxi;
            AH[m] = *(const s16x8*)&c1[imO[m] + r * 64 + (((kg + r) & 7) << 3)];
            AL[m] = *(const s16x8*)&c1[imO[m] + r * 64 + (((kg + 4 + r) & 7) << 3)];
          }
          __builtin_amdgcn_s_setprio(1);
#pragma unroll
          for (int m = 0; m < 5; ++m)
#pragma unroll
            for (int j = 0; j < 2; ++j)
              acc[m][j] = __builtin_amdgcn_mfma_f32_16x16x32_bf16(AH[m], BHc[j], acc[m][j], 0, 0, 0);
#pragma unroll
          for (int m = 0; m < 5; ++m)
#pragma unroll
            for (int j = 0; j < 2; ++j)
              acc[m][j] = __builtin_amdgcn_mfma_f32_16x16x32_bf16(AL[m], BHc[j], acc[m][j], 0, 0, 0);
#pragma unroll
          for (int m = 0; m < 5; ++m)
#pragma unroll
            for (int j = 0; j < 2; ++j)
              acc[m][j] = __builtin_amdgcn_mfma_f32_16x16x32_bf16(AH[m], BLc[j], acc[m][j], 0, 0, 0);
          __builtin_amdgcn_s_setprio(0);
#pragma unroll
          for (int j = 0; j < 2; ++j) { BHc[j] = BHn[j]; BLc[j] = BLn[j]; }
        }
      }
    }
  }

  // store partial: slot s = m*16 + kg*4 + jj -> (img, pos); col = r16 (co)
#pragma unroll
  for (int m = 0; m < 5; ++m) {
#pragma unroll
    for (int jj = 0; jj < 4; ++jj) {
      const int s = m * 16 + kg * 4 + jj;
      if (s < 72) {
        const int im = (s >= 36) ? 1 : 0;
        const int p = s - 36 * im;
#pragma unroll
        for (int j = 0; j < 2; ++j) {
          const int co = con[j];
          const int n = (co & 31) * 36 + p;
          xcp[((size_t)(img0 + im) * 1152 + n) * 8 + (co >> 5)] =
              acc[m][j][jj] + bias[j];
        }
      }
    }
  }
}

// ------- routing: 512 thr (32 ng x 16 k), LDS-staged x, shfl reductions -------
__global__ __launch_bounds__(512) void routing_fused(const float* __restrict__ xcaps0,
                                                     const float* __restrict__ xcaps1,
                                                     const float* __restrict__ W,
                                                     float* __restrict__ out) {
  const int o = blockIdx.x >> 7;     // 0..9 (o-major: same-o blocks share W)
  const int bp = blockIdx.x & 127;   // image pair
  const int b0 = bp * 2, b1 = b0 + 1;
  const int t = threadIdx.x;
  const int k = t & 15, ng = t >> 4;      // ng 0..31
  const int lane = t & 63, wavei = t >> 6; // 0..7
  __shared__ float xs0[1152 * 8];
  __shared__ float xs1[1152 * 8];
  __shared__ double srA[8][16], srB[8][16], srC[8][16], srD[8][16];
  __shared__ float s0s[16], s1s[16];
  __shared__ float sv0s, sv1s;
  __shared__ double f0s, f1s;

  {
    const float4* p00 = (const float4*)(xcaps0 + (size_t)b0 * 9216);
    const float4* p01 = (const float4*)(xcaps1 + (size_t)b0 * 9216);
    const float4* p10 = (const float4*)(xcaps0 + (size_t)b1 * 9216);
    const float4* p11 = (const float4*)(xcaps1 + (size_t)b1 * 9216);
    float4* d0 = (float4*)xs0;
    float4* d1 = (float4*)xs1;
    for (int i = t; i < 2304; i += 512) {
      float4 a = p00[i], b = p01[i];
      float4 c = p10[i], d = p11[i];
      float4 s0, s1;
      s0.x = a.x + b.x; s0.y = a.y + b.y; s0.z = a.z + b.z; s0.w = a.w + b.w;
      s1.x = c.x + d.x; s1.y = c.y + d.y; s1.z = c.z + d.z; s1.w = c.w + d.w;
      d0[i] = s0;
      d1[i] = s1;
    }
  }
  __syncthreads();

  const int n0 = ng * 36;
  float u0[36], u1[36];
  const float* wp = W + ((size_t)(n0 * 10 + o) * 16 + k) * 8;
#pragma unroll
  for (int i = 0; i < 36; ++i) {
    const float* wq = wp + (size_t)i * 1280;
    const float4 wa = *(const float4*)wq;
    const float4 wb = *(const float4*)(wq + 4);
    const float4 xa0 = *(const float4*)&xs0[(n0 + i) * 8];
    const float4 xb0 = *(const float4*)&xs0[(n0 + i) * 8 + 4];
    const float4 xa1 = *(const float4*)&xs1[(n0 + i) * 8];
    const float4 xb1 = *(const float4*)&xs1[(n0 + i) * 8 + 4];
    u0[i] = wa.x * xa0.x + wa.y * xa0.y + wa.z * xa0.z + wa.w * xa0.w
          + wb.x * xb0.x + wb.y * xb0.y + wb.z * xb0.z + wb.w * xb0.w;
    u1[i] = wa.x * xa1.x + wa.y * xa1.y + wa.z * xa1.z + wa.w * xa1.w
          + wb.x * xb1.x + wb.y * xb1.y + wb.z * xb1.z + wb.w * xb1.w;
  }

  // ---- pass 1: uniform c = 1/1152 ----
  {
    double S0 = 0.0, S1 = 0.0;
#pragma unroll
    for (int i = 0; i < 36; ++i) { S0 += (double)u0[i]; S1 += (double)u1[i]; }
    S0 += __shfl_xor(S0, 16); S0 += __shfl_xor(S0, 32);
    S1 += __shfl_xor(S1, 16); S1 += __shfl_xor(S1, 32);
    if (lane < 16) { srA[wavei][lane] = S0; srB[wavei][lane] = S1; }
  }
  __syncthreads();
  if (t < 32) {
    const int g = t >> 4, kk = t & 15;
    double tot = 0.0;
#pragma unroll
    for (int w = 0; w < 8; ++w) tot += (g == 0) ? srA[w][kk] : srB[w][kk];
    if (g == 0) s0s[kk] = (float)(tot * (double)(1.0f / 1152.0f));
    else        s1s[kk] = (float)(tot * (double)(1.0f / 1152.0f));
  }
  __syncthreads();
  if (t < 2) {
    const float* ss = (t == 0) ? s0s : s1s;
    double sn = 0.0;
#pragma unroll
    for (int kk = 0; kk < 16; ++kk) sn += (double)ss[kk] * (double)ss[kk];
    const double f = sn / ((1.0 + sn) * sqrt(sn));
    double sv = 0.0;
#pragma unroll
    for (int kk = 0; kk < 16; ++kk) sv += (double)ss[kk] * f;
    if (t == 0) sv0s = (float)sv; else sv1s = (float)sv;
  }
  __syncthreads();
  const float v10 = sv0s, v11 = sv1s;

  // ---- pass 2: logits u*sv1 ----
  {
    double E0 = 0.0, EU0 = 0.0, E1 = 0.0, EU1 = 0.0;
#pragma unroll
    for (int i = 0; i < 36; ++i) {
      const float e0 = expf(u0[i] * v10);
      E0 += (double)e0;
      EU0 += (double)e0 * (double)u0[i];
      const float e1 = expf(u1[i] * v11);
      E1 += (double)e1;
      EU1 += (double)e1 * (double)u1[i];
    }
    E0 += __shfl_xor(E0, 16); E0 += __shfl_xor(E0, 32);
    EU0 += __shfl_xor(EU0, 16); EU0 += __shfl_xor(EU0, 32);
    E1 += __shfl_xor(E1, 16); E1 += __shfl_xor(E1, 32);
    EU1 += __shfl_xor(EU1, 16); EU1 += __shfl_xor(EU1, 32);
    if (lane < 16) {
      srA[wavei][lane] = E0; srB[wavei][lane] = EU0;
      srC[wavei][lane] = E1; srD[wavei][lane] = EU1;
    }
  }
  __syncthreads();
  if (t < 32) {
    const int g = t >> 4, kk = t & 15;
    double te = 0.0, tu = 0.0;
#pragma unroll
    for (int w = 0; w < 8; ++w) {
      te += (g == 0) ? srA[w][kk] : srC[w][kk];
      tu += (g == 0) ? srB[w][kk] : srD[w][kk];
    }
    if (g == 0) s0s[kk] = (float)(tu / te);
    else        s1s[kk] = (float)(tu / te);
  }
  __syncthreads();
  if (t < 2) {
    const float* ss = (t == 0) ? s0s : s1s;
    double sn = 0.0;
#pragma unroll
    for (int kk = 0; kk < 16; ++kk) sn += (double)ss[kk] * (double)ss[kk];
    const double f = sn / ((1.0 + sn) * sqrt(sn));
    double sv = 0.0;
#pragma unroll
    for (int kk = 0; kk < 16; ++kk) sv += (double)ss[kk] * f;
    if (t == 0) sv0s = v10 + (float)sv; else sv1s = v11 + (float)sv;
  }
  __syncthreads();
  const float v20 = sv0s, v21 = sv1s;

  // ---- pass 3 -> output ----
  {
    double E0 = 0.0, EU0 = 0.0, E1 = 0.0, EU1 = 0.0;
#pragma unroll
    for (int i = 0; i < 36; ++i) {
      const float e0 = expf(u0[i] * v20);
      E0 += (double)e0;
      EU0 += (double)e0 * (double)u0[i];
      const float e1 = expf(u1[i] * v21);
      E1 += (double)e1;
      EU1 += (double)e1 * (double)u1[i];
    }
    E0 += __shfl_xor(E0, 16); E0 += __shfl_xor(E0, 32);
    EU0 += __shfl_xor(EU0, 16); EU0 += __shfl_xor(EU0, 32);
    E1 += __shfl_xor(E1, 16); E1 += __shfl_xor(E1, 32);
    EU1 += __shfl_xor(EU1, 16); EU1 += __shfl_xor(EU1, 32);
    if (lane < 16) {
      srA[wavei][lane] = E0; srB[wavei][lane] = EU0;
      srC[wavei][lane] = E1; srD[wavei][lane] = EU1;
    }
  }
  __syncthreads();
  if (t < 32) {
    const int g = t >> 4, kk = t & 15;
    double te = 0.0, tu = 0.0;
#pragma unroll
    for (int w = 0; w < 8; ++w) {
      te += (g == 0) ? srA[w][kk] : srC[w][kk];
      tu += (g == 0) ? srB[w][kk] : srD[w][kk];
    }
    if (g == 0) s0s[kk] = (float)(tu / te);
    else        s1s[kk] = (float)(tu / te);
  }
  __syncthreads();
  if (t < 2) {
    const float* ss = (t == 0) ? s0s : s1s;
    double sn = 0.0;
#pragma unroll
    for (int kk = 0; kk < 16; ++kk) sn += (double)ss[kk] * (double)ss[kk];
    if (t == 0) f0s = sn / ((1.0 + sn) * sqrt(sn));
    else        f1s = sn / ((1.0 + sn) * sqrt(sn));
  }
  __syncthreads();
  if (t < 32) {
    const int g = t >> 4, kk = t & 15;
    const int b = (g == 0) ? b0 : b1;
    const double f = (g == 0) ? f0s : f1s;
    const float s = (g == 0) ? s0s[kk] : s1s[kk];
    out[b * 160 + o * 16 + kk] = (float)((double)s * f);
  }
}

extern "C" void kernel_launch(void* const* d_in, const int* in_sizes, int n_in,
                              void* d_out, int out_size, void* d_ws, size_t ws_size,
                              hipStream_t stream) {
  const float* data = (const float*)d_in[0];
  const float* w1   = (const float*)d_in[1];
  const float* b1   = (const float*)d_in[2];
  const float* w2   = (const float*)d_in[3];
  const float* b2   = (const float*)d_in[4];
  const float* W    = (const float*)d_in[5];
  float* out = (float*)d_out;

  short* wstg   = (short*)d_ws;               // 10,616,832 shorts (21.2 MB)
  short* c1g    = wstg + 10616832;            // 48,234,496 shorts (96.5 MB)
  float* xcaps0 = (float*)(c1g + 48234496);   //  2,359,296 floats (9.4 MB)
  float* xcaps1 = xcaps0 + 2359296;           //  2,359,296 floats (9.4 MB)

  prep_all<<<1024, 256, 0, stream>>>(w2, (s16x8*)wstg, data, w1, b1, c1g);
  conv2_mfma<<<512, 256, 0, stream>>>(c1g, wstg, b2, xcaps0, xcaps1);
  routing_fused<<<1280, 512, 0, stream>>>(xcaps0, xcaps1, W, out);
}